// Round 7
// baseline (187.993 us; speedup 1.0000x reference)
//
#include <hip/hip_runtime.h>

typedef unsigned short u16;
typedef __attribute__((ext_vector_type(8))) short bf16x8;   // MFMA A/B frag (8 bf16)
typedef __attribute__((ext_vector_type(4))) float f32x4;    // 16x16 C/D frag
typedef __attribute__((ext_vector_type(16))) float f32x16;  // 32x32 C/D frag

#define MFMA16(a, b, c) __builtin_amdgcn_mfma_f32_16x16x32_bf16((a), (b), (c), 0, 0, 0)
#define MFMA32(a, b, c) __builtin_amdgcn_mfma_f32_32x32x16_bf16((a), (b), (c), 0, 0, 0)

// async global->LDS, 16B per lane; LDS dest = wave-uniform base + lane*16
__device__ __forceinline__ void gll16(const void* g, void* l) {
    __builtin_amdgcn_global_load_lds(
        (const __attribute__((address_space(1))) unsigned int*)g,
        (__attribute__((address_space(3))) unsigned int*)l, 16, 0, 0);
}

__device__ __forceinline__ u16 f2b(float f) {   // f32 -> bf16 RNE (scalar)
    unsigned int u = __float_as_uint(f);
    u += 0x7fffu + ((u >> 16) & 1u);
    return (u16)(u >> 16);
}

// packed bf16x2 via HW converter (RNE): lo=cvt(a), hi=cvt(b).
__device__ __forceinline__ unsigned int pkcvt(float a, float b) {
    unsigned int r;
    asm("v_cvt_pk_bf16_f32 %0, %1, %2" : "=v"(r) : "v"(a), "v"(b));
    return r;
}

// ---------------------------------------------------------------- one cast kernel
__global__ __launch_bounds__(256) void cast_all(const float* __restrict__ x,
                                                const float* __restrict__ w0,
                                                const float* __restrict__ w1,
                                                const float* __restrict__ w2,
                                                const float* __restrict__ w3,
                                                u16* __restrict__ xb,
                                                u16* __restrict__ wb) {
    const int bid = blockIdx.x;
    const float* s; u16* d; int off;
    if (bid < 2048) { s = x; d = xb; off = bid; }
    else {
        const int wi = (bid - 2048) >> 9;
        s = (wi == 0) ? w0 : (wi == 1) ? w1 : (wi == 2) ? w2 : w3;
        d = wb + (size_t)wi * 1048576;
        off = (bid - 2048) & 511;
    }
    const int i = (off * 256 + threadIdx.x) * 8;
    float4 a = *(const float4*)(s + i);
    float4 b = *(const float4*)(s + i + 4);
    *(uint4*)(d + i) = make_uint4(pkcvt(a.x, a.y), pkcvt(a.z, a.w),
                                  pkcvt(b.x, b.y), pkcvt(b.z, b.w));
}

// ---------------------------------------------------------------- GEMM, dbuf K-loop
// (unchanged from R4 — proven: QKV 128^2 @3/CU, o-proj 128x64 @2/CU)
template <int BM, int BN, int MODE, int SLOTS>
__global__ __launch_bounds__(256) void gemm_bt(const u16* __restrict__ A,
                                               const u16* __restrict__ W,
                                               void* __restrict__ Yv,
                                               u16* __restrict__ vT,
                                               int K, int ldY) {
    constexpr int MI = BM / 32, NJ = BN / 32;
    constexpr int ACH = BM / 16;
    constexpr int NPW = (BM + BN) / 64;
    __shared__ u16 As[2][SLOTS][BM * 32];
    __shared__ u16 Bs[2][SLOTS][BN * 32];
    const int t = threadIdx.x, w = t >> 6, lane = t & 63;
    const int quad = lane >> 4, m16 = lane & 15;
    const int wr = (w >> 1) * (BM / 2), wc = (w & 1) * (BN / 2);
    const int row0 = blockIdx.x * BM, col0 = blockIdx.y * BN;
    const int srow = lane >> 2, scol = (lane & 3) * 8;

    auto stage = [&](int buf, int slot, int k0) {
#pragma unroll
        for (int cc = 0; cc < NPW; ++cc) {
            const int c = w * NPW + cc;
            if (c < ACH)
                gll16(A + (size_t)(row0 + c * 16 + srow) * K + k0 + scol,
                      &As[buf][slot][c * 512]);
            else
                gll16(W + (size_t)(col0 + (c - ACH) * 16 + srow) * K + k0 + scol,
                      &Bs[buf][slot][(c - ACH) * 512]);
        }
    };

    f32x4 acc[MI][NJ];
#pragma unroll
    for (int i = 0; i < MI; ++i)
#pragma unroll
        for (int j = 0; j < NJ; ++j) acc[i][j] = (f32x4){0.f, 0.f, 0.f, 0.f};

    auto compute_tile = [&](int buf, int slot) {
        bf16x8 af[MI], bf[NJ];
#pragma unroll
        for (int i = 0; i < MI; ++i)
            af[i] = *(const bf16x8*)&As[buf][slot][(wr + i * 16 + m16) * 32 + quad * 8];
#pragma unroll
        for (int j = 0; j < NJ; ++j)
            bf[j] = *(const bf16x8*)&Bs[buf][slot][(wc + j * 16 + m16) * 32 + quad * 8];
#pragma unroll
        for (int i = 0; i < MI; ++i)
#pragma unroll
            for (int j = 0; j < NJ; ++j) acc[i][j] = MFMA16(af[i], bf[j], acc[i][j]);
    };

#pragma unroll
    for (int s = 0; s < SLOTS; ++s) stage(0, s, s * 32);
    const int ngroups = K / (32 * SLOTS);
    for (int g = 0; g < ngroups; ++g) {
        const int buf = g & 1;
        __syncthreads();
        const int kn = (g + 1) * SLOTS * 32;
        if (kn < K) {
#pragma unroll
            for (int s = 0; s < SLOTS; ++s) stage(buf ^ 1, s, kn + s * 32);
        }
#pragma unroll
        for (int s = 0; s < SLOTS; ++s) compute_tile(buf, s);
    }
    if constexpr (MODE == 0) {
#pragma unroll
        for (int i = 0; i < MI; ++i)
#pragma unroll
            for (int j = 0; j < NJ; ++j)
#pragma unroll
                for (int r = 0; r < 4; ++r)
                    ((float*)Yv)[(size_t)(row0 + wr + i * 16 + quad * 4 + r) * ldY +
                                 col0 + wc + j * 16 + m16] = acc[i][j][r];
    } else {
        if (col0 < 2048) {
            u16* qk = (u16*)Yv;
#pragma unroll
            for (int i = 0; i < MI; ++i)
#pragma unroll
                for (int j = 0; j < NJ; ++j)
#pragma unroll
                    for (int r = 0; r < 4; ++r)
                        qk[(size_t)(row0 + wr + i * 16 + quad * 4 + r) * 2048 +
                           col0 + wc + j * 16 + m16] = f2b(acc[i][j][r]);
        } else {
#pragma unroll
            for (int i = 0; i < MI; ++i) {
                const int rbase = row0 + wr + i * 16;
                const int bb = rbase >> 10;
                const int tok0 = (rbase & 1023) + quad * 4;
#pragma unroll
                for (int j = 0; j < NJ; ++j) {
                    const int vTrow = bb * 1024 + (col0 + wc + j * 16 + m16 - 2048);
                    *(uint2*)(vT + (size_t)vTrow * 1024 + tok0) =
                        make_uint2(pkcvt(acc[i][j][0], acc[i][j][1]),
                                   pkcvt(acc[i][j][2], acc[i][j][3]));
                }
            }
        }
    }
}

// ---------------------------------------------------------------- based attention, 32x32
// R7: balance + swizzle fix of R6 (R6 PMC: MfmaUtil 7.3%, 53% wave-idle from
// per-block pairing; 3.3M LDS bank conflicts).
//  - block q owns CONSECUTIVE subtiles j = 4q + w: per-wave work {2q+1,2q+1,
//    2q+2,2q+2} (<=1 tile skew); inter-block imbalance absorbed by 512-block
//    grid + dynamic refill. VGPR ~100 -> ~4 blocks/CU.
//  - T2 swizzle via PRE-SWIZZLED gll16 source (LDS stays linear, rule #21):
//    stage lane fetches src slot (l&3)^((l>>2)&3); reads XOR slot with row&3.
//    16-way -> 8-way conflicts.
// In-register S (T12): QK^T D-layout keeps q=lane&31 lane-local; S->PV A-operand
// = 16 pkcvt + 16 shfl_xor(32). den = extra MFMA column (B=ones).
__global__ __launch_bounds__(256) void based_attn32(const u16* __restrict__ qkm,
                                                    const u16* __restrict__ vT,
                                                    u16* __restrict__ o) {
    __shared__ u16 ks[2][2][64][32];   // [buf][dblk][key][32 dims]  16KB
    __shared__ u16 vs[2][2][64][32];   // [buf][kblk][vdim][32 keys] 16KB

    const int t = threadIdx.x, w = t >> 6, lane = t & 63;
    const int m = lane & 31, h = lane >> 5;
    const int q = blockIdx.x, hh = blockIdx.y, b = blockIdx.z;
    const int j = 4 * q + w;                 // wave's 32-row q-subtile
    const int ktmax_w = j >> 1;              // this wave's last key-tile
    const int KTMAX = 2 * q + 1;             // block staging bound (= max j>>1)
    const int srow = lane >> 2;
    const int s8x = (((lane & 3) ^ ((lane >> 2) & 3)) * 8);  // pre-swizzled src slot

    const size_t qbase = (size_t)b * 1024 * 2048 + hh * 64;
    const size_t kbase = qbase + 1024;
    const size_t vbase = ((size_t)b * 1024 + hh * 64) * 1024;

    // Q frags: lane supplies q-row (col) = m, dims kd*16 + h*8 .. +7
    bf16x8 qf[4];
#pragma unroll
    for (int kd = 0; kd < 4; ++kd)
        qf[kd] = *(const bf16x8*)(qkm + qbase + (size_t)(j * 32 + m) * 2048 +
                                  kd * 16 + h * 8);

    auto stage_tile = [&](int kt, int buf) {
#pragma unroll
        for (int cc = 0; cc < 2; ++cc) {
            const int c = w * 2 + cc;
            const int blk = c >> 2, rc = c & 3;
            gll16(qkm + kbase + (size_t)(kt * 64 + rc * 16 + srow) * 2048 + blk * 32 + s8x,
                  &ks[buf][blk][rc * 16][0]);
            gll16(vT + vbase + (size_t)(rc * 16 + srow) * 1024 + kt * 64 + blk * 32 + s8x,
                  &vs[buf][blk][rc * 16][0]);
        }
    };

    bf16x8 ones;
#pragma unroll
    for (int e = 0; e < 8; ++e) ones[e] = (short)0x3F80;

    f32x16 num0, num1, den;
#pragma unroll
    for (int e = 0; e < 16; ++e) { num0[e] = 0.f; num1[e] = 0.f; den[e] = 0.f; }

    const int mx3 = m & 3;                   // row&3 for rows m and 32+m alike

    auto compute = [&](int buf, int kt) {
        const bool diag = (kt == ktmax_w);
        const bool odd = (j & 1) != 0;
        const bool do1 = (!diag) || odd;     // key-chunk 1 has any live scores?

        // ---- QK^T: S^T chunks [32 keys][32 q], K-dim 64 in 4 steps of 16
        f32x16 s0, s1;
#pragma unroll
        for (int e = 0; e < 16; ++e) { s0[e] = 0.f; s1[e] = 0.f; }
#pragma unroll
        for (int kd = 0; kd < 4; ++kd) {
            const int sl = (((kd & 1) * 2 + h) ^ mx3) * 8;   // swizzled slot
            bf16x8 k0 = *(const bf16x8*)&ks[buf][kd >> 1][m][sl];
            s0 = MFMA32(k0, qf[kd], s0);
            if (do1) {
                bf16x8 k1 = *(const bf16x8*)&ks[buf][kd >> 1][32 + m][sl];
                s1 = MFMA32(k1, qf[kd], s1);
            }
        }

        // ---- transform + causal mask (register-resident)
        // D layout: col(q)=lane&31, row(key_local)=(r&3)+8*(r>>2)+4*h
        float sc0[16], sc1[16];
#pragma unroll
        for (int r = 0; r < 16; ++r) {
            const int kl = (r & 3) + 8 * (r >> 2) + 4 * h;
            float u0 = fmaf(s0[r], 0.125f, 1.0f);
            float v0 = fmaf(u0 * 0.5f, u0, 0.5f);
            if (diag && !odd && kl > m) v0 = 0.f;
            sc0[r] = v0;
            float v1 = 0.f;
            if (do1) {
                float u1 = fmaf(s1[r], 0.125f, 1.0f);
                v1 = fmaf(u1 * 0.5f, u1, 0.5f);
                if (diag && odd && kl > m) v1 = 0.f;
            }
            sc1[r] = v1;
        }

        // ---- pack to bf16 + half-exchange (lane <-> lane^32)
        unsigned o0[8], o1[8], p0[8], p1[8];
#pragma unroll
        for (int i = 0; i < 8; ++i) {
            o0[i] = pkcvt(sc0[2 * i], sc0[2 * i + 1]);
            o1[i] = pkcvt(sc1[2 * i], sc1[2 * i + 1]);
        }
#pragma unroll
        for (int i = 0; i < 8; ++i) {
            p0[i] = __shfl_xor(o0[i], 32);
            p1[i] = __shfl_xor(o1[i], 32);
        }

        // ---- PV + den: A = S[q][k] (row=q=lane&31), B = V[k][vd] (col=vd)
#pragma unroll
        for (int ksi = 0; ksi < 4; ++ksi) {
            const int bx = (ksi & 1) * 4 + 2 * h;     // pk index base
            union { unsigned u[4]; bf16x8 v; } af;
            if (ksi < 2) {
                af.u[0] = h ? p0[bx] : o0[bx];
                af.u[1] = h ? p0[bx + 1] : o0[bx + 1];
                af.u[2] = h ? o0[bx] : p0[bx];
                af.u[3] = h ? o0[bx + 1] : p0[bx + 1];
            } else {
                af.u[0] = h ? p1[bx] : o1[bx];
                af.u[1] = h ? p1[bx + 1] : o1[bx + 1];
                af.u[2] = h ? o1[bx] : p1[bx];
                af.u[3] = h ? o1[bx + 1] : p1[bx + 1];
            }
            const int sl = (((ksi & 1) * 2 + h) ^ mx3) * 8;   // swizzled slot
            bf16x8 v0 = *(const bf16x8*)&vs[buf][ksi >> 1][m][sl];
            bf16x8 v1 = *(const bf16x8*)&vs[buf][ksi >> 1][32 + m][sl];
            num0 = MFMA32(af.v, v0, num0);
            num1 = MFMA32(af.v, v1, num1);
            den  = MFMA32(af.v, ones, den);
        }
    };

    stage_tile(0, 0);
    for (int kt = 0; kt <= KTMAX; ++kt) {
        const int buf = kt & 1;
        __syncthreads();                      // tile kt landed; buf^1 free
        if (kt < KTMAX) stage_tile(kt + 1, buf ^ 1);
        if (kt <= ktmax_w) compute(buf, kt);
    }

    // ---- epilogue: o[tok][hh*64 + vd] = num/den
#pragma unroll
    for (int r = 0; r < 16; ++r) {
        const int qq = (r & 3) + 8 * (r >> 2) + 4 * h;
        const float inv = 1.0f / den[r];
        const size_t tok = (size_t)(b * 1024 + j * 32 + qq);
        o[tok * 1024 + hh * 64 + m]      = f2b(num0[r] * inv);
        o[tok * 1024 + hh * 64 + 32 + m] = f2b(num1[r] * inv);
    }
}

// ---------------------------------------------------------------- launch
extern "C" void kernel_launch(void* const* d_in, const int* in_sizes, int n_in,
                              void* d_out, int out_size, void* d_ws, size_t ws_size,
                              hipStream_t stream) {
    const float* x  = (const float*)d_in[0];
    const float* Wq = (const float*)d_in[1];
    const float* Wk = (const float*)d_in[2];
    const float* Wv = (const float*)d_in[3];
    const float* Wo = (const float*)d_in[4];
    float* out = (float*)d_out;

    const size_t MEL = 4096ull * 1024ull;        // 4M elements
    u16* xb   = (u16*)d_ws;                      // 4096 x 1024
    u16* Wqkv = xb + MEL;                        // 3072 x 1024 (Wq|Wk|Wv rows)
    u16* Wob  = Wqkv + 3ull * 1024 * 1024;       // 1024 x 1024
    u16* qk   = Wob + 1024ull * 1024;            // 4096 x 2048 (q|k)
    u16* vT   = qk + 2ull * MEL;                 // [b*1024+h*64+vd][1024 tokens]
    u16* o    = vT + MEL;                        // 4096 x 1024

    cast_all<<<4096, 256, 0, stream>>>(x, Wq, Wk, Wv, Wo, xb, Wqkv);

    dim3 gq(32, 24);   // 128^2, 768 blocks = 3/CU (proven 39.4 us)
    gemm_bt<128, 128, 1, 1><<<gq, 256, 0, stream>>>(xb, Wqkv, qk, vT, 1024, 2048);

    // R7: balanced consecutive-j mapping + swizzled staging
    dim3 ga(8, 16, 4); // j-group x heads x batch
    based_attn32<<<ga, 256, 0, stream>>>(qk, vT, o);

    dim3 go(32, 16);   // o-proj 128x64, 512 blocks = 2/CU (proven R4 win)
    gemm_bt<128, 64, 0, 2><<<go, 256, 0, stream>>>(o, Wob, (void*)out, nullptr, 1024, 1024);
}

// Round 8
// 168.797 us; speedup vs baseline: 1.1137x; 1.1137x over previous
//
#include <hip/hip_runtime.h>

typedef unsigned short u16;
typedef __attribute__((ext_vector_type(8))) short bf16x8;   // MFMA A/B frag (8 bf16)
typedef __attribute__((ext_vector_type(4))) float f32x4;    // MFMA C/D frag

#define MFMA16(a, b, c) __builtin_amdgcn_mfma_f32_16x16x32_bf16((a), (b), (c), 0, 0, 0)

// async global->LDS, 16B per lane; LDS dest = wave-uniform base + lane*16
__device__ __forceinline__ void gll16(const void* g, void* l) {
    __builtin_amdgcn_global_load_lds(
        (const __attribute__((address_space(1))) unsigned int*)g,
        (__attribute__((address_space(3))) unsigned int*)l, 16, 0, 0);
}

__device__ __forceinline__ u16 f2b(float f) {   // f32 -> bf16 RNE (scalar)
    unsigned int u = __float_as_uint(f);
    u += 0x7fffu + ((u >> 16) & 1u);
    return (u16)(u >> 16);
}

// packed bf16x2 via HW converter (RNE)
__device__ __forceinline__ unsigned int pkcvt(float a, float b) {
    unsigned int r;
    asm("v_cvt_pk_bf16_f32 %0, %1, %2" : "=v"(r) : "v"(a), "v"(b));
    return r;
}

// compile-time vmcnt waits (immediate must be literal)
template <int N> __device__ __forceinline__ void waitv();
template <> __device__ __forceinline__ void waitv<0>() { asm volatile("s_waitcnt vmcnt(0)" ::: "memory"); }
template <> __device__ __forceinline__ void waitv<3>() { asm volatile("s_waitcnt vmcnt(3)" ::: "memory"); }
template <> __device__ __forceinline__ void waitv<4>() { asm volatile("s_waitcnt vmcnt(4)" ::: "memory"); }
template <> __device__ __forceinline__ void waitv<6>() { asm volatile("s_waitcnt vmcnt(6)" ::: "memory"); }
template <> __device__ __forceinline__ void waitv<8>() { asm volatile("s_waitcnt vmcnt(8)" ::: "memory"); }

// ---------------------------------------------------------------- one cast kernel
__global__ __launch_bounds__(256) void cast_all(const float* __restrict__ x,
                                                const float* __restrict__ w0,
                                                const float* __restrict__ w1,
                                                const float* __restrict__ w2,
                                                const float* __restrict__ w3,
                                                u16* __restrict__ xb,
                                                u16* __restrict__ wb) {
    const int bid = blockIdx.x;
    const float* s; u16* d; int off;
    if (bid < 2048) { s = x; d = xb; off = bid; }
    else {
        const int wi = (bid - 2048) >> 9;
        s = (wi == 0) ? w0 : (wi == 1) ? w1 : (wi == 2) ? w2 : w3;
        d = wb + (size_t)wi * 1048576;
        off = (bid - 2048) & 511;
    }
    const int i = (off * 256 + threadIdx.x) * 8;
    float4 a = *(const float4*)(s + i);
    float4 b = *(const float4*)(s + i + 4);
    *(uint4*)(d + i) = make_uint4(pkcvt(a.x, a.y), pkcvt(a.z, a.w),
                                  pkcvt(b.x, b.y), pkcvt(b.z, b.w));
}

// ---------------------------------------------------------------- GEMM, TRI-buffered
// R8: 128-class tiles, 4 waves (2x2), BK=32, THREE LDS buffers; counted-vmcnt
// protocol (stage kt+3 two compute-phases ahead; never vmcnt(0) in steady state):
//   per iter: waitv<2N> -> s_barrier (tile kt landed for ALL waves) ->
//             compute(buf) -> s_barrier (all reads done) -> stage(buf, kt+3).
// Keeps proven geometry: QKV 128x128 @ 768 blocks (3/CU, 48KB LDS), o-proj
// 128x64 @ 512 blocks (36KB LDS). MODE 0: f32 out. MODE 1: fused QKV epilogue.
template <int BM, int BN, int MODE>
__global__ __launch_bounds__(256) void gemm_bt3(const u16* __restrict__ A,
                                                const u16* __restrict__ W,
                                                void* __restrict__ Yv,
                                                u16* __restrict__ vT,
                                                int K, int ldY) {
    constexpr int MI = BM / 32, NJ = BN / 32;
    constexpr int ACH = BM / 16;                   // A staging chunks (1KB each)
    constexpr int NPW = (BM + BN) / 64;            // gll16 per wave per stage
    __shared__ u16 As[3][BM * 32];
    __shared__ u16 Bs[3][BN * 32];
    const int t = threadIdx.x, w = t >> 6, lane = t & 63;
    const int quad = lane >> 4, m16 = lane & 15;
    const int wr = (w >> 1) * (BM / 2), wc = (w & 1) * (BN / 2);
    const int row0 = blockIdx.x * BM, col0 = blockIdx.y * BN;
    const int srow = lane >> 2, scol = (lane & 3) * 8;

    auto stage = [&](int buf, int k0) {
#pragma unroll
        for (int cc = 0; cc < NPW; ++cc) {
            const int c = w * NPW + cc;
            if (c < ACH)
                gll16(A + (size_t)(row0 + c * 16 + srow) * K + k0 + scol,
                      &As[buf][c * 512]);
            else
                gll16(W + (size_t)(col0 + (c - ACH) * 16 + srow) * K + k0 + scol,
                      &Bs[buf][(c - ACH) * 512]);
        }
    };

    f32x4 acc[MI][NJ];
#pragma unroll
    for (int i = 0; i < MI; ++i)
#pragma unroll
        for (int j = 0; j < NJ; ++j) acc[i][j] = (f32x4){0.f, 0.f, 0.f, 0.f};

    auto compute_tile = [&](int buf) {
        bf16x8 af[MI], bf[NJ];
#pragma unroll
        for (int i = 0; i < MI; ++i)
            af[i] = *(const bf16x8*)&As[buf][(wr + i * 16 + m16) * 32 + quad * 8];
#pragma unroll
        for (int j = 0; j < NJ; ++j)
            bf[j] = *(const bf16x8*)&Bs[buf][(wc + j * 16 + m16) * 32 + quad * 8];
#pragma unroll
        for (int i = 0; i < MI; ++i)
#pragma unroll
            for (int j = 0; j < NJ; ++j) acc[i][j] = MFMA16(af[i], bf[j], acc[i][j]);
    };

    const int NKT = K / 32;                        // requires >= 3
    stage(0, 0); stage(1, 32); stage(2, 64);
    int buf = 0;
    for (int kt = 0; kt < NKT; ++kt) {
        if (kt < NKT - 2)      waitv<2 * NPW>();   // own kt-loads landed; kt+1,kt+2 fly
        else if (kt == NKT - 2) waitv<NPW>();
        else                    waitv<0>();
        __builtin_amdgcn_s_barrier();              // all waves' kt-loads landed
        __builtin_amdgcn_sched_barrier(0);         // rule #18: pin ds_read below
        compute_tile(buf);
        __builtin_amdgcn_s_barrier();              // all waves done reading buf
        const int kn = (kt + 3) * 32;
        if (kn < K) stage(buf, kn);
        buf = (buf == 2) ? 0 : buf + 1;
    }

    if constexpr (MODE == 0) {
#pragma unroll
        for (int i = 0; i < MI; ++i)
#pragma unroll
            for (int j = 0; j < NJ; ++j)
#pragma unroll
                for (int r = 0; r < 4; ++r)
                    ((float*)Yv)[(size_t)(row0 + wr + i * 16 + quad * 4 + r) * ldY +
                                 col0 + wc + j * 16 + m16] = acc[i][j][r];
    } else {
        if (col0 < 2048) {              // Q/K projection -> bf16, stride 2048
            u16* qk = (u16*)Yv;
#pragma unroll
            for (int i = 0; i < MI; ++i)
#pragma unroll
                for (int j = 0; j < NJ; ++j)
#pragma unroll
                    for (int r = 0; r < 4; ++r)
                        qk[(size_t)(row0 + wr + i * 16 + quad * 4 + r) * 2048 +
                           col0 + wc + j * 16 + m16] = f2b(acc[i][j][r]);
        } else {                        // V projection -> transposed vT
#pragma unroll
            for (int i = 0; i < MI; ++i) {
                const int rbase = row0 + wr + i * 16;
                const int bb = rbase >> 10;
                const int tok0 = (rbase & 1023) + quad * 4;
#pragma unroll
                for (int j = 0; j < NJ; ++j) {
                    const int vTrow = bb * 1024 + (col0 + wc + j * 16 + m16 - 2048);
                    *(uint2*)(vT + (size_t)vTrow * 1024 + tok0) =
                        make_uint2(pkcvt(acc[i][j][0], acc[i][j][1]),
                                   pkcvt(acc[i][j][2], acc[i][j][3]));
                }
            }
        }
    }
}

// ---------------------------------------------------------------- based attention
// REVERTED to R4's measured-best 16x16 kernel (160.7 us build): triangular
// pairing (tA=p, tB=15-p), per-wave-uniform work, LDS-staged k/v, Q in regs,
// TWO kt-tiles per barrier, dbuf. pkcvt + setprio kept (neutral).
// R6/R7 32x32 experiments: 54.6/63.6 us vs ~33 here — structure abandoned.
__global__ __launch_bounds__(256) void based_attn(const u16* __restrict__ qkm,
                                                  const u16* __restrict__ vT,
                                                  u16* __restrict__ o) {
    __shared__ u16 ks[2][2][2][64][32];  // [buf][slot][dblk][key][32]
    __shared__ u16 vs[2][2][2][64][32];  // [buf][slot][kb][vdim][32 keys]
    __shared__ u16 SsA[2][64][32];       // [kb][qrow][32 keys] (wave-private rows)
    __shared__ u16 SsB[2][64][32];

    const int t = threadIdx.x, w = t >> 6, lane = t & 63;
    const int quad = lane >> 4, m16 = lane & 15;
    const int p = blockIdx.x, h = blockIdx.y, b = blockIdx.z;
    const int tA = p, tB = 15 - p;
    const int srow = lane >> 2, s8 = (lane & 3) * 8;
    const int qrow = w * 16 + m16;       // this lane's q-row (local to tile)

    const size_t qbase = (size_t)b * 1024 * 2048 + h * 64;   // + row*2048
    const size_t kbase = qbase + 1024;
    const size_t vbase = ((size_t)b * 1024 + h * 64) * 1024; // + vd*1024 + tok

    bf16x8 qfA[2], qfB[2];
#pragma unroll
    for (int kd = 0; kd < 2; ++kd) {
        qfA[kd] = *(const bf16x8*)(qkm + qbase +
                   (size_t)(tA * 64 + qrow) * 2048 + kd * 32 + quad * 8);
        qfB[kd] = *(const bf16x8*)(qkm + qbase +
                   (size_t)(tB * 64 + qrow) * 2048 + kd * 32 + quad * 8);
    }

    auto stage_tile = [&](int kt, int buf, int slot) {
#pragma unroll
        for (int cc = 0; cc < 2; ++cc) {
            const int c = w * 2 + cc;
            const int blk = c >> 2, rc = c & 3;
            gll16(qkm + kbase + (size_t)(kt * 64 + rc * 16 + srow) * 2048 + blk * 32 + s8,
                  &ks[buf][slot][blk][rc * 16][0]);
            gll16(vT + vbase + (size_t)(rc * 16 + srow) * 1024 + kt * 64 + blk * 32 + s8,
                  &vs[buf][slot][blk][rc * 16][0]);
        }
    };

    bf16x8 ones;
#pragma unroll
    for (int e = 0; e < 8; ++e) ones[e] = (short)0x3F80;

    f32x4 numA[4], numB[4], denA, denB;
    denA = denB = (f32x4){0.f, 0.f, 0.f, 0.f};
#pragma unroll
    for (int j = 0; j < 4; ++j) numA[j] = numB[j] = (f32x4){0.f, 0.f, 0.f, 0.f};

    auto compute = [&](int buf, int slot, int kt) {
        const bool doA = (kt <= tA);
        f32x4 sA[4], sB[4];
#pragma unroll
        for (int jk = 0; jk < 4; ++jk)
            sA[jk] = sB[jk] = (f32x4){0.f, 0.f, 0.f, 0.f};
        __builtin_amdgcn_s_setprio(1);
#pragma unroll
        for (int kd = 0; kd < 2; ++kd)
#pragma unroll
            for (int jk = 0; jk < 4; ++jk) {
                bf16x8 af = *(const bf16x8*)&ks[buf][slot][kd][jk * 16 + m16][quad * 8];
                sB[jk] = MFMA16(af, qfB[kd], sB[jk]);
                if (doA) sA[jk] = MFMA16(af, qfA[kd], sA[jk]);
            }
        __builtin_amdgcn_s_setprio(0);
#pragma unroll
        for (int jk = 0; jk < 4; ++jk) {
            const int kl = jk * 16 + quad * 4;
            float scB[4];
#pragma unroll
            for (int r = 0; r < 4; ++r) {
                const float u = fmaf(sB[jk][r], 0.125f, 1.0f);
                scB[r] = fmaf(u * 0.5f, u, 0.5f);
            }
            if (kt == tB) {
#pragma unroll
                for (int r = 0; r < 4; ++r)
                    if (kl + r > qrow) scB[r] = 0.f;
            }
            *(uint2*)&SsB[kl >> 5][qrow][kl & 31] =
                make_uint2(pkcvt(scB[0], scB[1]), pkcvt(scB[2], scB[3]));
            if (doA) {
                float scA[4];
#pragma unroll
                for (int r = 0; r < 4; ++r) {
                    const float u = fmaf(sA[jk][r], 0.125f, 1.0f);
                    scA[r] = fmaf(u * 0.5f, u, 0.5f);
                }
                if (kt == tA) {
#pragma unroll
                    for (int r = 0; r < 4; ++r)
                        if (kl + r > qrow) scA[r] = 0.f;
                }
                *(uint2*)&SsA[kl >> 5][qrow][kl & 31] =
                    make_uint2(pkcvt(scA[0], scA[1]), pkcvt(scA[2], scA[3]));
            }
        }
        __builtin_amdgcn_s_setprio(1);
#pragma unroll
        for (int kb = 0; kb < 2; ++kb) {
            bf16x8 vf[4];
#pragma unroll
            for (int j = 0; j < 4; ++j)
                vf[j] = *(const bf16x8*)&vs[buf][slot][kb][j * 16 + m16][quad * 8];
            bf16x8 sfB = *(const bf16x8*)&SsB[kb][qrow][quad * 8];
#pragma unroll
            for (int j = 0; j < 4; ++j) numB[j] = MFMA16(sfB, vf[j], numB[j]);
            denB = MFMA16(sfB, ones, denB);
            if (doA) {
                bf16x8 sfA = *(const bf16x8*)&SsA[kb][qrow][quad * 8];
#pragma unroll
                for (int j = 0; j < 4; ++j) numA[j] = MFMA16(sfA, vf[j], numA[j]);
                denA = MFMA16(sfA, ones, denA);
            }
        }
        __builtin_amdgcn_s_setprio(0);
    };

    stage_tile(0, 0, 0);
    stage_tile(1, 0, 1);

    const int ngroups = (tB + 2) >> 1;
    for (int g = 0; g < ngroups; ++g) {
        const int buf = g & 1;
        __syncthreads();
        const int kn = (g + 1) * 2;
        if (kn <= tB) {
            stage_tile(kn, buf ^ 1, 0);
            if (kn + 1 <= tB) stage_tile(kn + 1, buf ^ 1, 1);
        }
        const int kt0 = g * 2;
        compute(buf, 0, kt0);
        if (kt0 + 1 <= tB) compute(buf, 1, kt0 + 1);
    }

#pragma unroll
    for (int r = 0; r < 4; ++r) {
        const float invA = 1.0f / denA[r], invB = 1.0f / denB[r];
        const int rowoff = w * 16 + quad * 4 + r;
        const size_t tokA = (size_t)(b * 1024 + tA * 64 + rowoff);
        const size_t tokB = (size_t)(b * 1024 + tB * 64 + rowoff);
#pragma unroll
        for (int j = 0; j < 4; ++j) {
            o[tokA * 1024 + h * 64 + j * 16 + m16] = f2b(numA[j][r] * invA);
            o[tokB * 1024 + h * 64 + j * 16 + m16] = f2b(numB[j][r] * invB);
        }
    }
}

// ---------------------------------------------------------------- launch
extern "C" void kernel_launch(void* const* d_in, const int* in_sizes, int n_in,
                              void* d_out, int out_size, void* d_ws, size_t ws_size,
                              hipStream_t stream) {
    const float* x  = (const float*)d_in[0];
    const float* Wq = (const float*)d_in[1];
    const float* Wk = (const float*)d_in[2];
    const float* Wv = (const float*)d_in[3];
    const float* Wo = (const float*)d_in[4];
    float* out = (float*)d_out;

    const size_t MEL = 4096ull * 1024ull;        // 4M elements
    u16* xb   = (u16*)d_ws;                      // 4096 x 1024
    u16* Wqkv = xb + MEL;                        // 3072 x 1024 (Wq|Wk|Wv rows)
    u16* Wob  = Wqkv + 3ull * 1024 * 1024;       // 1024 x 1024
    u16* qk   = Wob + 1024ull * 1024;            // 4096 x 2048 (q|k)
    u16* vT   = qk + 2ull * MEL;                 // [b*1024+h*64+vd][1024 tokens]
    u16* o    = vT + MEL;                        // 4096 x 1024

    cast_all<<<4096, 256, 0, stream>>>(x, Wq, Wk, Wv, Wo, xb, Wqkv);

    // R8: tri-buffered counted-vmcnt at proven 128^2 geometry (768 blocks, 3/CU)
    dim3 gq(32, 24);
    gemm_bt3<128, 128, 1><<<gq, 256, 0, stream>>>(xb, Wqkv, qk, vT, 1024, 2048);

    dim3 ga(8, 16, 4); // pair index x heads x batch — uniform work per block
    based_attn<<<ga, 256, 0, stream>>>(qk, vT, o);

    // R8: o-proj same tri protocol, 128x64 (512 blocks, 36KB LDS)
    dim3 go(32, 16);
    gemm_bt3<128, 64, 0><<<go, 256, 0, stream>>>(o, Wob, (void*)out, nullptr, 1024, 1024);
}

// Round 11
// 163.291 us; speedup vs baseline: 1.1513x; 1.0337x over previous
//
#include <hip/hip_runtime.h>

typedef unsigned short u16;
typedef __attribute__((ext_vector_type(8))) short bf16x8;   // MFMA A/B frag (8 bf16)
typedef __attribute__((ext_vector_type(4))) short s16x4;    // 4 bf16 (K=16 A/B frag)
typedef __attribute__((ext_vector_type(2))) int i32x2;      // same 8 bytes as s16x4
typedef __attribute__((ext_vector_type(4))) float f32x4;    // MFMA C/D frag

#define MFMA16(a, b, c) __builtin_amdgcn_mfma_f32_16x16x32_bf16((a), (b), (c), 0, 0, 0)

// K=16 bf16 MFMA. Prefer the builtin (compiler-managed MFMA hazards/scheduling);
// fall back to inline asm only if the builtin is missing on this toolchain.
__device__ __forceinline__ void mfma161616(i32x2 a, i32x2 b, f32x4& c) {
#if __has_builtin(__builtin_amdgcn_mfma_f32_16x16x16bf16_1k)
    union { i32x2 i; s16x4 s; } ua{a}, ub{b};
    c = __builtin_amdgcn_mfma_f32_16x16x16bf16_1k(ua.s, ub.s, c, 0, 0, 0);
#else
    asm("v_mfma_f32_16x16x16_bf16 %0, %1, %2, %0" : "+v"(c) : "v"(a), "v"(b));
#endif
}

// async global->LDS, 16B per lane; LDS dest = wave-uniform base + lane*16
__device__ __forceinline__ void gll16(const void* g, void* l) {
    __builtin_amdgcn_global_load_lds(
        (const __attribute__((address_space(1))) unsigned int*)g,
        (__attribute__((address_space(3))) unsigned int*)l, 16, 0, 0);
}

__device__ __forceinline__ u16 f2b(float f) {   // f32 -> bf16 RNE (scalar)
    unsigned int u = __float_as_uint(f);
    u += 0x7fffu + ((u >> 16) & 1u);
    return (u16)(u >> 16);
}

// packed bf16x2 via HW converter (RNE)
__device__ __forceinline__ unsigned int pkcvt(float a, float b) {
    unsigned int r;
    asm("v_cvt_pk_bf16_f32 %0, %1, %2" : "=v"(r) : "v"(a), "v"(b));
    return r;
}

// ---------------------------------------------------------------- one cast kernel
__global__ __launch_bounds__(256) void cast_all(const float* __restrict__ x,
                                                const float* __restrict__ w0,
                                                const float* __restrict__ w1,
                                                const float* __restrict__ w2,
                                                const float* __restrict__ w3,
                                                u16* __restrict__ xb,
                                                u16* __restrict__ wb) {
    const int bid = blockIdx.x;
    const float* s; u16* d; int off;
    if (bid < 2048) { s = x; d = xb; off = bid; }
    else {
        const int wi = (bid - 2048) >> 9;
        s = (wi == 0) ? w0 : (wi == 1) ? w1 : (wi == 2) ? w2 : w3;
        d = wb + (size_t)wi * 1048576;
        off = (bid - 2048) & 511;
    }
    const int i = (off * 256 + threadIdx.x) * 8;
    float4 a = *(const float4*)(s + i);
    float4 b = *(const float4*)(s + i + 4);
    *(uint4*)(d + i) = make_uint4(pkcvt(a.x, a.y), pkcvt(a.z, a.w),
                                  pkcvt(b.x, b.y), pkcvt(b.z, b.w));
}

// ---------------------------------------------------------------- GEMM, dbuf K-loop
// R4-proven structure (R8 tri-buffer counted-vmcnt regressed +8us — 3rd
// null/negative for counted-vmcnt outside full 8-phase interleave).
// QKV: 128x128, 768 blocks (3/CU). o-proj: 128x64, 512 blocks (2/CU), SLOTS=2.
template <int BM, int BN, int MODE, int SLOTS>
__global__ __launch_bounds__(256) void gemm_bt(const u16* __restrict__ A,
                                               const u16* __restrict__ W,
                                               void* __restrict__ Yv,
                                               u16* __restrict__ vT,
                                               int K, int ldY) {
    constexpr int MI = BM / 32, NJ = BN / 32;
    constexpr int ACH = BM / 16;
    constexpr int NPW = (BM + BN) / 64;
    __shared__ u16 As[2][SLOTS][BM * 32];
    __shared__ u16 Bs[2][SLOTS][BN * 32];
    const int t = threadIdx.x, w = t >> 6, lane = t & 63;
    const int quad = lane >> 4, m16 = lane & 15;
    const int wr = (w >> 1) * (BM / 2), wc = (w & 1) * (BN / 2);
    const int row0 = blockIdx.x * BM, col0 = blockIdx.y * BN;
    const int srow = lane >> 2, scol = (lane & 3) * 8;

    auto stage = [&](int buf, int slot, int k0) {
#pragma unroll
        for (int cc = 0; cc < NPW; ++cc) {
            const int c = w * NPW + cc;
            if (c < ACH)
                gll16(A + (size_t)(row0 + c * 16 + srow) * K + k0 + scol,
                      &As[buf][slot][c * 512]);
            else
                gll16(W + (size_t)(col0 + (c - ACH) * 16 + srow) * K + k0 + scol,
                      &Bs[buf][slot][(c - ACH) * 512]);
        }
    };

    f32x4 acc[MI][NJ];
#pragma unroll
    for (int i = 0; i < MI; ++i)
#pragma unroll
        for (int j = 0; j < NJ; ++j) acc[i][j] = (f32x4){0.f, 0.f, 0.f, 0.f};

    auto compute_tile = [&](int buf, int slot) {
        bf16x8 af[MI], bf[NJ];
#pragma unroll
        for (int i = 0; i < MI; ++i)
            af[i] = *(const bf16x8*)&As[buf][slot][(wr + i * 16 + m16) * 32 + quad * 8];
#pragma unroll
        for (int j = 0; j < NJ; ++j)
            bf[j] = *(const bf16x8*)&Bs[buf][slot][(wc + j * 16 + m16) * 32 + quad * 8];
#pragma unroll
        for (int i = 0; i < MI; ++i)
#pragma unroll
            for (int j = 0; j < NJ; ++j) acc[i][j] = MFMA16(af[i], bf[j], acc[i][j]);
    };

#pragma unroll
    for (int s = 0; s < SLOTS; ++s) stage(0, s, s * 32);
    const int ngroups = K / (32 * SLOTS);
    for (int g = 0; g < ngroups; ++g) {
        const int buf = g & 1;
        __syncthreads();
        const int kn = (g + 1) * SLOTS * 32;
        if (kn < K) {
#pragma unroll
            for (int s = 0; s < SLOTS; ++s) stage(buf ^ 1, s, kn + s * 32);
        }
#pragma unroll
        for (int s = 0; s < SLOTS; ++s) compute_tile(buf, s);
    }
    if constexpr (MODE == 0) {
#pragma unroll
        for (int i = 0; i < MI; ++i)
#pragma unroll
            for (int j = 0; j < NJ; ++j)
#pragma unroll
                for (int r = 0; r < 4; ++r)
                    ((float*)Yv)[(size_t)(row0 + wr + i * 16 + quad * 4 + r) * ldY +
                                 col0 + wc + j * 16 + m16] = acc[i][j][r];
    } else {
        if (col0 < 2048) {
            u16* qk = (u16*)Yv;
#pragma unroll
            for (int i = 0; i < MI; ++i)
#pragma unroll
                for (int j = 0; j < NJ; ++j)
#pragma unroll
                    for (int r = 0; r < 4; ++r)
                        qk[(size_t)(row0 + wr + i * 16 + quad * 4 + r) * 2048 +
                           col0 + wc + j * 16 + m16] = f2b(acc[i][j][r]);
        } else {
#pragma unroll
            for (int i = 0; i < MI; ++i) {
                const int rbase = row0 + wr + i * 16;
                const int bb = rbase >> 10;
                const int tok0 = (rbase & 1023) + quad * 4;
#pragma unroll
                for (int j = 0; j < NJ; ++j) {
                    const int vTrow = bb * 1024 + (col0 + wc + j * 16 + m16 - 2048);
                    *(uint2*)(vT + (size_t)vTrow * 1024 + tok0) =
                        make_uint2(pkcvt(acc[i][j][0], acc[i][j][1]),
                                   pkcvt(acc[i][j][2], acc[i][j][3]));
                }
            }
        }
    }
}

// ---------------------------------------------------------------- based attention
// R9/R10: zero-LDS-S PV. QK^T (16x16x32) leaves S^T in regs with col=q=lane&15,
// row=key=quad*4+r — EXACTLY the B-operand layout of v_mfma_f32_16x16x16_bf16.
// PV computed transposed: num^T[vd][q] += MFMA16x16x16(V^T_frag, S_frag): the two
// pkcvt packs per 16-key chunk ARE the B-frag; no Ss LDS buffer, no same-wave
// write->read round-trip. den = per-lane scalar sum + 2 shfl_xor (was 4 MFMAs).
// LDS 80KB -> 64KB; epilogue 8 coalesced uint2 stores (was 32 scattered u16).
// Structure else = R4 proven: tA=p/tB=15-p pairing, 2 kt-tiles per barrier, dbuf.
__global__ __launch_bounds__(256) void based_attn(const u16* __restrict__ qkm,
                                                  const u16* __restrict__ vT,
                                                  u16* __restrict__ o) {
    __shared__ u16 ks[2][2][2][64][32];  // [buf][slot][dblk][key][32]   32KB
    __shared__ u16 vs[2][2][2][64][32];  // [buf][slot][kblk][vdim][32]  32KB

    const int t = threadIdx.x, w = t >> 6, lane = t & 63;
    const int quad = lane >> 4, m16 = lane & 15;
    const int p = blockIdx.x, h = blockIdx.y, b = blockIdx.z;
    const int tA = p, tB = 15 - p;
    const int srow = lane >> 2, s8 = (lane & 3) * 8;
    const int qrow = w * 16 + m16;       // this lane's q-row (local to tile)

    const size_t qbase = (size_t)b * 1024 * 2048 + h * 64;
    const size_t kbase = qbase + 1024;
    const size_t vbase = ((size_t)b * 1024 + h * 64) * 1024;

    bf16x8 qfA[2], qfB[2];
#pragma unroll
    for (int kd = 0; kd < 2; ++kd) {
        qfA[kd] = *(const bf16x8*)(qkm + qbase +
                   (size_t)(tA * 64 + qrow) * 2048 + kd * 32 + quad * 8);
        qfB[kd] = *(const bf16x8*)(qkm + qbase +
                   (size_t)(tB * 64 + qrow) * 2048 + kd * 32 + quad * 8);
    }

    auto stage_tile = [&](int kt, int buf, int slot) {
#pragma unroll
        for (int cc = 0; cc < 2; ++cc) {
            const int c = w * 2 + cc;
            const int blk = c >> 2, rc = c & 3;
            gll16(qkm + kbase + (size_t)(kt * 64 + rc * 16 + srow) * 2048 + blk * 32 + s8,
                  &ks[buf][slot][blk][rc * 16][0]);
            gll16(vT + vbase + (size_t)(rc * 16 + srow) * 1024 + kt * 64 + blk * 32 + s8,
                  &vs[buf][slot][blk][rc * 16][0]);
        }
    };

    f32x4 numA[4], numB[4];              // num^T: row=vd(quad*4+r in j-tile), col=q
    float densA = 0.f, densB = 0.f;      // per-lane partial of den[q=m16]
#pragma unroll
    for (int j = 0; j < 4; ++j) numA[j] = numB[j] = (f32x4){0.f, 0.f, 0.f, 0.f};

    auto compute = [&](int buf, int slot, int kt) {
        const bool doA = (kt <= tA);
        // ---- Phase 1: S^T = K * Q^T (shared K-frags for both units)
        f32x4 sA[4], sB[4];
#pragma unroll
        for (int jk = 0; jk < 4; ++jk)
            sA[jk] = sB[jk] = (f32x4){0.f, 0.f, 0.f, 0.f};
        __builtin_amdgcn_s_setprio(1);
#pragma unroll
        for (int kd = 0; kd < 2; ++kd)
#pragma unroll
            for (int jk = 0; jk < 4; ++jk) {
                bf16x8 af = *(const bf16x8*)&ks[buf][slot][kd][jk * 16 + m16][quad * 8];
                sB[jk] = MFMA16(af, qfB[kd], sB[jk]);
                if (doA) sA[jk] = MFMA16(af, qfA[kd], sA[jk]);
            }
        __builtin_amdgcn_s_setprio(0);
        // ---- transform + mask + pack (register-resident S)
        i32x2 sbA[4], sbB[4];
#pragma unroll
        for (int jk = 0; jk < 4; ++jk) {
            const int kl = jk * 16 + quad * 4;
            float scB[4];
#pragma unroll
            for (int r = 0; r < 4; ++r) {
                const float u = fmaf(sB[jk][r], 0.125f, 1.0f);
                scB[r] = fmaf(u * 0.5f, u, 0.5f);
            }
            if (kt == tB) {
#pragma unroll
                for (int r = 0; r < 4; ++r)
                    if (kl + r > qrow) scB[r] = 0.f;
            }
            densB += scB[0] + scB[1] + scB[2] + scB[3];
            sbB[jk][0] = (int)pkcvt(scB[0], scB[1]);
            sbB[jk][1] = (int)pkcvt(scB[2], scB[3]);
            if (doA) {
                float scA[4];
#pragma unroll
                for (int r = 0; r < 4; ++r) {
                    const float u = fmaf(sA[jk][r], 0.125f, 1.0f);
                    scA[r] = fmaf(u * 0.5f, u, 0.5f);
                }
                if (kt == tA) {
#pragma unroll
                    for (int r = 0; r < 4; ++r)
                        if (kl + r > qrow) scA[r] = 0.f;
                }
                densA += scA[0] + scA[1] + scA[2] + scA[3];
                sbA[jk][0] = (int)pkcvt(scA[0], scA[1]);
                sbA[jk][1] = (int)pkcvt(scA[2], scA[3]);
            }
        }
        // ---- Phase 2: num^T += V^T * S  (K=16 MFMA; S straight from regs)
        __builtin_amdgcn_s_setprio(1);
#pragma unroll
        for (int jk = 0; jk < 4; ++jk) {
            const int kb = jk >> 1, ko = (jk & 1) * 16 + quad * 4;
#pragma unroll
            for (int j = 0; j < 4; ++j) {
                i32x2 va = *(const i32x2*)&vs[buf][slot][kb][j * 16 + m16][ko];
                mfma161616(va, sbB[jk], numB[j]);
                if (doA) mfma161616(va, sbA[jk], numA[j]);
            }
        }
        __builtin_amdgcn_s_setprio(0);
    };

    stage_tile(0, 0, 0);
    stage_tile(1, 0, 1);

    const int ngroups = (tB + 2) >> 1;
    for (int g = 0; g < ngroups; ++g) {
        const int buf = g & 1;
        __syncthreads();
        const int kn = (g + 1) * 2;
        if (kn <= tB) {
            stage_tile(kn, buf ^ 1, 0);
            if (kn + 1 <= tB) stage_tile(kn + 1, buf ^ 1, 1);
        }
        const int kt0 = g * 2;
        compute(buf, 0, kt0);
        if (kt0 + 1 <= tB) compute(buf, 1, kt0 + 1);
    }

    // ---- den reduce across quads (4 lanes share q=m16), then epilogue
    densA += __shfl_xor(densA, 16); densA += __shfl_xor(densA, 32);
    densB += __shfl_xor(densB, 16); densB += __shfl_xor(densB, 32);
    const float invA = 1.0f / densA, invB = 1.0f / densB;
    const size_t tokA = (size_t)(b * 1024 + tA * 64 + qrow);
    const size_t tokB = (size_t)(b * 1024 + tB * 64 + qrow);
#pragma unroll
    for (int j = 0; j < 4; ++j) {
        *(uint2*)(o + tokA * 1024 + h * 64 + j * 16 + quad * 4) =
            make_uint2(pkcvt(numA[j][0] * invA, numA[j][1] * invA),
                       pkcvt(numA[j][2] * invA, numA[j][3] * invA));
        *(uint2*)(o + tokB * 1024 + h * 64 + j * 16 + quad * 4) =
            make_uint2(pkcvt(numB[j][0] * invB, numB[j][1] * invB),
                       pkcvt(numB[j][2] * invB, numB[j][3] * invB));
    }
}

// ---------------------------------------------------------------- launch
extern "C" void kernel_launch(void* const* d_in, const int* in_sizes, int n_in,
                              void* d_out, int out_size, void* d_ws, size_t ws_size,
                              hipStream_t stream) {
    const float* x  = (const float*)d_in[0];
    const float* Wq = (const float*)d_in[1];
    const float* Wk = (const float*)d_in[2];
    const float* Wv = (const float*)d_in[3];
    const float* Wo = (const float*)d_in[4];
    float* out = (float*)d_out;

    const size_t MEL = 4096ull * 1024ull;        // 4M elements
    u16* xb   = (u16*)d_ws;                      // 4096 x 1024
    u16* Wqkv = xb + MEL;                        // 3072 x 1024 (Wq|Wk|Wv rows)
    u16* Wob  = Wqkv + 3ull * 1024 * 1024;       // 1024 x 1024
    u16* qk   = Wob + 1024ull * 1024;            // 4096 x 2048 (q|k)
    u16* vT   = qk + 2ull * MEL;                 // [b*1024+h*64+vd][1024 tokens]
    u16* o    = vT + MEL;                        // 4096 x 1024

    cast_all<<<4096, 256, 0, stream>>>(x, Wq, Wk, Wv, Wo, xb, Wqkv);

    dim3 gq(32, 24);   // 128^2, 768 blocks = 3/CU (R4 proven)
    gemm_bt<128, 128, 1, 1><<<gq, 256, 0, stream>>>(xb, Wqkv, qk, vT, 1024, 2048);

    // zero-LDS-S attention (PV^T via K=16 MFMA, S in registers)
    dim3 ga(8, 16, 4); // pair index x heads x batch — uniform work per block
    based_attn<<<ga, 256, 0, stream>>>(qk, vT, o);

    dim3 go(32, 16);   // o-proj 128x64, 512 blocks = 2/CU (R4 proven)
    gemm_bt<128, 64, 0, 2><<<go, 256, 0, stream>>>(o, Wob, (void*)out, nullptr, 1024, 1024);
}